// Round 4
// baseline (101.556 us; speedup 1.0000x reference)
//
#include <hip/hip_runtime.h>
#include <hip/hip_bf16.h>

// Fused causal attention, S=2048 B=2 H=16 D=128, sbhd, fp32 in/out, bf16 MFMA.
// Round 4: 32 q-rows/wave (QBLK=128), fragment-linear LDS chunks with
// conflict-free sigma-swizzle and zero per-read address VALU, paired q-tiles
// (uniform 34 kv-tiles/block), double-buffered LDS, exp2-domain softmax.

#define DDIM    128
#define ROWSTR  4096          // B*H*D element stride along s/t
#define QBLK    128
#define KVBLK   64
#define NQT     16            // 2048 / QBLK
#define QSCALE  0.1275174190023967f   // (1/sqrt(128)) * log2(e)

typedef __attribute__((ext_vector_type(4))) float f32x4;
typedef __attribute__((ext_vector_type(8))) short s16x8;

__device__ inline unsigned pk2bf(float a, float b) {
    union { __hip_bfloat162 h; unsigned u; } cv;
    cv.h = __float22bfloat162_rn(float2{a, b});
    return cv.u;
}

// LDS chunk layout: 16 chunks of 1024 B per operand (K: f = m*4+kk over
// kv-rowblock m, d-chunk kk; V: f = db*2 + kvhalf). Within a chunk, lane
// slot sigma(r,g',f) = (r ^ ((g'^phi)&3) ^ ((psi ^ (r>>3))<<2)) + 16*g',
// phi=(f>>1)&3, psi=f&1.  Reads: ds_read_b128 at rbase[f&7] + f*1024
// (single base VGPR + immediate). Both write patterns and reads hit
// 8 granules x 8 lanes = conflict-free.

__global__ __launch_bounds__(256, 1)
void fattn_kernel(const float* __restrict__ q, const float* __restrict__ k,
                  const float* __restrict__ v, float* __restrict__ out)
{
    __shared__ char lds[2][32768];   // [buf][ K 16KB | V 16KB ]

    const int tid = threadIdx.x;
    const int w = tid >> 6, l = tid & 63, g = l >> 4, lr = l & 15;
    const int bid = blockIdx.x;
    const int bh = bid & 31;          // same-head blocks share an XCD (bid%8)
    const int pr = bid >> 5;          // 0..7 pair index

    const float* qbh = q + bh * DDIM;
    const float* kbh = k + bh * DDIM;
    const float* vbh = v + bh * DDIM;

    // ---- 8 read bases (per f&7), computed once
    int rbase[8];
#pragma unroll
    for (int j8 = 0; j8 < 8; ++j8) {
        int phi = (j8 >> 1) & 3, psi = j8 & 1;
        int slot = (lr ^ ((g ^ phi) & 3) ^ ((psi ^ (lr >> 3)) << 2)) + 16 * g;
        rbase[j8] = slot * 16;
    }

    // staging maps
    const int krow0 = tid >> 4;          // K: r (0..15), rows krow0+16j
    const int kg    = tid & 3;           // K: g'
    const int kk2   = (tid & 15) >> 2;   // K: d-chunk kk
    const int vq4   = tid & 31;          // V: d quad (dd = 4*vq4+jj)
    const int vc    = tid >> 5;          // V: kv chunk 0..7
    const int vhalf = vc >> 2, vg = vc & 3;

    f32x4 kreg[8], vreg[8];

    auto prefetch = [&](int kv0) {
        const float* kp = kbh + (size_t)(kv0 + krow0) * ROWSTR + (tid & 15) * 8;
#pragma unroll
        for (int j = 0; j < 4; ++j) {
            kreg[2 * j]     = *(const f32x4*)(kp + (size_t)(16 * j) * ROWSTR);
            kreg[2 * j + 1] = *(const f32x4*)(kp + (size_t)(16 * j) * ROWSTR + 4);
        }
        // V rows for slot (vhalf, vg): kv = 32*vhalf + 4*vg + i and +16
        const float* vp = vbh + (size_t)(kv0 + 32 * vhalf + 4 * vg) * ROWSTR + vq4 * 4;
#pragma unroll
        for (int i = 0; i < 4; ++i) {
            vreg[i]     = *(const f32x4*)(vp + (size_t)i * ROWSTR);
            vreg[4 + i] = *(const f32x4*)(vp + (size_t)(16 + i) * ROWSTR);
        }
    };

    auto stage = [&](char* base) {
#pragma unroll
        for (int j = 0; j < 4; ++j) {
            int f = 4 * j + kk2;
            int phi = (f >> 1) & 3, psi = f & 1;
            int slot = (krow0 ^ ((kg ^ phi) & 3) ^ ((psi ^ (krow0 >> 3)) << 2)) + 16 * kg;
            s16x8 t; unsigned* tu = (unsigned*)&t;
            tu[0] = pk2bf(kreg[2 * j][0],     kreg[2 * j][1]);
            tu[1] = pk2bf(kreg[2 * j][2],     kreg[2 * j][3]);
            tu[2] = pk2bf(kreg[2 * j + 1][0], kreg[2 * j + 1][1]);
            tu[3] = pk2bf(kreg[2 * j + 1][2], kreg[2 * j + 1][3]);
            *(s16x8*)(base + f * 1024 + slot * 16) = t;
        }
#pragma unroll
        for (int jj = 0; jj < 4; ++jj) {
            int dd = 4 * vq4 + jj;
            int f = (dd >> 4) * 2 + vhalf;
            int phi = (dd >> 4) & 3, psi = vhalf;
            int r = dd & 15;
            int slot = (r ^ ((vg ^ phi) & 3) ^ ((psi ^ (r >> 3)) << 2)) + 16 * vg;
            s16x8 t; unsigned* tu = (unsigned*)&t;
            tu[0] = pk2bf(vreg[0][jj], vreg[1][jj]);
            tu[1] = pk2bf(vreg[2][jj], vreg[3][jj]);
            tu[2] = pk2bf(vreg[4][jj], vreg[5][jj]);
            tu[3] = pk2bf(vreg[6][jj], vreg[7][jj]);
            *(s16x8*)(base + 16384 + f * 1024 + slot * 16) = t;
        }
    };

    const int qtA = pr, qtB = NQT - 1 - pr;
    const int ntA = 2 * pr + 2, ntB = 2 * (NQT - 1 - pr) + 2;
    const int total = ntA + ntB;        // uniform 34

    int qb  = qtA * QBLK;
    int qr0 = qb + 32 * w + lr;         // qh=0 row; qh=1 row = qr0+16

    s16x8 qf[2][4];
    auto load_qf = [&]() {
#pragma unroll
        for (int qh = 0; qh < 2; ++qh)
#pragma unroll
            for (int kk = 0; kk < 4; ++kk) {
                const float* qp = qbh + (size_t)(qr0 + 16 * qh) * ROWSTR + kk * 32 + g * 8;
                f32x4 a = *(const f32x4*)qp, b = *(const f32x4*)(qp + 4);
                unsigned* tu = (unsigned*)&qf[qh][kk];
                tu[0] = pk2bf(a[0] * QSCALE, a[1] * QSCALE);
                tu[1] = pk2bf(a[2] * QSCALE, a[3] * QSCALE);
                tu[2] = pk2bf(b[0] * QSCALE, b[1] * QSCALE);
                tu[3] = pk2bf(b[2] * QSCALE, b[3] * QSCALE);
            }
    };
    load_qf();

    f32x4 acc[8][2];
#pragma unroll
    for (int i = 0; i < 8; ++i) { acc[i][0] = (f32x4){0,0,0,0}; acc[i][1] = (f32x4){0,0,0,0}; }
    float mrun[2] = { -INFINITY, -INFINITY };
    float lrun[2] = { 0.f, 0.f };

    auto kv_of = [&](int tt) { return (tt < ntA ? tt : tt - ntA) * KVBLK; };

    prefetch(0);
    stage(lds[0]);
    prefetch(kv_of(1));
    __syncthreads();

    for (int tt = 0; tt < total; ++tt) {
        const int cur = tt & 1;
        const bool phB = tt >= ntA;
        const int t  = phB ? tt - ntA : tt;
        const int nt = phB ? ntB : ntA;

        if (tt + 1 < total) {
            stage(lds[cur ^ 1]);                    // tile tt+1 (regs ready)
            if (tt + 2 < total) prefetch(kv_of(tt + 2));
        }

        const char* bK = lds[cur];
        const char* bV = lds[cur] + 16384;
        const int kv0 = t * KVBLK;
        const int wqmin = qb + 32 * w;              // wave's min q-row

        if (kv0 <= wqmin + 31) {                    // wave-uniform causal skip
            // ---- S^T = K · Q^T : sa[m][qh], kv = kv0+16m+4g+r, q = qr0+16qh
            f32x4 sa[4][2];
#pragma unroll
            for (int m = 0; m < 4; ++m) { sa[m][0] = (f32x4){0,0,0,0}; sa[m][1] = (f32x4){0,0,0,0}; }
#pragma unroll
            for (int m = 0; m < 4; ++m)
#pragma unroll
                for (int kk = 0; kk < 4; ++kk) {
                    int f = 4 * m + kk;
                    s16x8 kf = *(const s16x8*)(bK + rbase[f & 7] + f * 1024);
                    sa[m][0] = __builtin_amdgcn_mfma_f32_16x16x32_bf16(kf, qf[0][kk], sa[m][0], 0, 0, 0);
                    sa[m][1] = __builtin_amdgcn_mfma_f32_16x16x32_bf16(kf, qf[1][kk], sa[m][1], 0, 0, 0);
                }

            const bool maskt = (kv0 + KVBLK - 1 > wqmin);
            float mxv[2];
#pragma unroll
            for (int qh = 0; qh < 2; ++qh) {
                int qrow = qr0 + 16 * qh;
                if (maskt) {
#pragma unroll
                    for (int m = 0; m < 4; ++m)
#pragma unroll
                        for (int r = 0; r < 4; ++r)
                            if (kv0 + 16 * m + 4 * g + r > qrow) sa[m][qh][r] = -INFINITY;
                }
                float mx = sa[0][qh][0];
#pragma unroll
                for (int m = 0; m < 4; ++m)
#pragma unroll
                    for (int r = 0; r < 4; ++r) mx = fmaxf(mx, sa[m][qh][r]);
                mx = fmaxf(mx, __shfl_xor(mx, 16));
                mx = fmaxf(mx, __shfl_xor(mx, 32));
                mxv[qh] = mx;
            }

            if (!__all((mxv[0] - mrun[0] <= 8.0f) && (mxv[1] - mrun[1] <= 8.0f))) {
#pragma unroll
                for (int qh = 0; qh < 2; ++qh) {
                    float mnew = fmaxf(mrun[qh], mxv[qh]);
                    float corr = __builtin_amdgcn_exp2f(mrun[qh] - mnew);
                    lrun[qh] *= corr;
#pragma unroll
                    for (int db = 0; db < 8; ++db)
#pragma unroll
                        for (int r = 0; r < 4; ++r) acc[db][qh][r] *= corr;
                    mrun[qh] = mnew;
                }
            }

#pragma unroll
            for (int qh = 0; qh < 2; ++qh) {
                float ts = 0.f;
#pragma unroll
                for (int m = 0; m < 4; ++m)
#pragma unroll
                    for (int r = 0; r < 4; ++r) {
                        float p = __builtin_amdgcn_exp2f(sa[m][qh][r] - mrun[qh]);
                        sa[m][qh][r] = p;
                        ts += p;
                    }
                ts += __shfl_xor(ts, 16);
                ts += __shfl_xor(ts, 32);
                lrun[qh] += ts;
            }

            // ---- pack P: pa[qh][hf] element (g,j) = P[q][kv0+32hf+16(j>>2)+4g+(j&3)]
            s16x8 pa[2][2];
#pragma unroll
            for (int qh = 0; qh < 2; ++qh)
#pragma unroll
                for (int hf = 0; hf < 2; ++hf) {
                    unsigned* pu = (unsigned*)&pa[qh][hf];
                    pu[0] = pk2bf(sa[2 * hf][qh][0],     sa[2 * hf][qh][1]);
                    pu[1] = pk2bf(sa[2 * hf][qh][2],     sa[2 * hf][qh][3]);
                    pu[2] = pk2bf(sa[2 * hf + 1][qh][0], sa[2 * hf + 1][qh][1]);
                    pu[3] = pk2bf(sa[2 * hf + 1][qh][2], sa[2 * hf + 1][qh][3]);
                }

            // ---- O^T += V^T · P^T
#pragma unroll
            for (int db = 0; db < 8; ++db)
#pragma unroll
                for (int hf = 0; hf < 2; ++hf) {
                    int f = 2 * db + hf;
                    s16x8 vf = *(const s16x8*)(bV + rbase[f & 7] + f * 1024);
                    acc[db][0] = __builtin_amdgcn_mfma_f32_16x16x32_bf16(vf, pa[0][hf], acc[db][0], 0, 0, 0);
                    acc[db][1] = __builtin_amdgcn_mfma_f32_16x16x32_bf16(vf, pa[1][hf], acc[db][1], 0, 0, 0);
                }
        }

        if (t == nt - 1) {
            // ---- epilogue: lane holds O[qr0+16qh][d = db*16 + 4g + r]
#pragma unroll
            for (int qh = 0; qh < 2; ++qh) {
                float inv = 1.0f / lrun[qh];
                float* op = out + (size_t)(qr0 + 16 * qh) * ROWSTR + bh * DDIM;
#pragma unroll
                for (int db = 0; db < 8; ++db) {
                    f32x4 o;
#pragma unroll
                    for (int r = 0; r < 4; ++r) o[r] = acc[db][qh][r] * inv;
                    *(f32x4*)(op + db * 16 + g * 4) = o;
                }
            }
            if (!phB) {                             // reset for phase B
#pragma unroll
                for (int i = 0; i < 8; ++i) { acc[i][0] = (f32x4){0,0,0,0}; acc[i][1] = (f32x4){0,0,0,0}; }
                mrun[0] = mrun[1] = -INFINITY;
                lrun[0] = lrun[1] = 0.f;
                qb  = qtB * QBLK;
                qr0 = qb + 32 * w + lr;
                load_qf();
            }
        }
        __syncthreads();
    }
}

extern "C" void kernel_launch(void* const* d_in, const int* in_sizes, int n_in,
                              void* d_out, int out_size, void* d_ws, size_t ws_size,
                              hipStream_t stream) {
    const float* q = (const float*)d_in[0];
    const float* k = (const float*)d_in[1];
    const float* v = (const float*)d_in[2];
    float* o = (float*)d_out;
    dim3 grid(32 * 8);    // bh-major: a head's 8 pair-blocks share an XCD
    dim3 block(256);
    fattn_kernel<<<grid, block, 0, stream>>>(q, k, v, o);
}

// Round 5
// 94.708 us; speedup vs baseline: 1.0723x; 1.0723x over previous
//
#include <hip/hip_runtime.h>
#include <hip/hip_bf16.h>

// Fused causal attention, S=2048 B=2 H=16 D=128, sbhd, fp32 in/out, bf16 MFMA.
// Round 5: 32 q-rows/wave (QBLK=128), fragment-linear conflict-free LDS,
// grid=512 (2 blocks/CU, all co-resident), complementary qt pairing via
// dispatch order, double-buffered LDS, exp2 softmax, setprio around MFMA.

#define DDIM    128
#define ROWSTR  4096          // B*H*D element stride along s/t
#define QBLK    128
#define KVBLK   64
#define NQT     16            // 2048 / QBLK
#define QSCALE  0.1275174190023967f   // (1/sqrt(128)) * log2(e)

typedef __attribute__((ext_vector_type(4))) float f32x4;
typedef __attribute__((ext_vector_type(8))) short s16x8;

__device__ inline unsigned pk2bf(float a, float b) {
    union { __hip_bfloat162 h; unsigned u; } cv;
    cv.h = __float22bfloat162_rn(float2{a, b});
    return cv.u;
}

// LDS chunk layout: 16 chunks of 1024 B per operand (K: f = m*4+kk over
// kv-rowblock m, d-chunk kk; V: f = db*2 + kvhalf). Within a chunk, lane
// slot sigma(r,g',f) = (r ^ ((g'^phi)&3) ^ ((psi ^ (r>>3))<<2)) + 16*g',
// phi=(f>>1)&3, psi=f&1.  Reads: ds_read_b128 at rbase[f&7] + f*1024
// (single base VGPR + immediate). Writes and reads both conflict-free.

__global__ __launch_bounds__(256, 2)
void fattn_kernel(const float* __restrict__ q, const float* __restrict__ k,
                  const float* __restrict__ v, float* __restrict__ out)
{
    __shared__ char lds[2][32768];   // [buf][ K 16KB | V 16KB ]

    const int tid = threadIdx.x;
    const int w = tid >> 6, l = tid & 63, g = l >> 4, lr = l & 15;
    const int bid = blockIdx.x;
    const int bh = bid & 31;          // same-head blocks share an XCD (32%8==0)
    const int j  = bid >> 5;          // 0..15
    // complementary co-residency pairing: blocks i and i+256 share a CU slot;
    // qt(j) + qt(j+8) == 15  ->  every CU gets 34 kv-tile-units.
    const int qt = (j < 8) ? (15 - 2 * j) : (2 * j - 16);

    const float* qbh = q + bh * DDIM;
    const float* kbh = k + bh * DDIM;
    const float* vbh = v + bh * DDIM;

    // ---- 8 read bases (per f&7), computed once
    int rbase[8];
#pragma unroll
    for (int j8 = 0; j8 < 8; ++j8) {
        int phi = (j8 >> 1) & 3, psi = j8 & 1;
        int slot = (lr ^ ((g ^ phi) & 3) ^ ((psi ^ (lr >> 3)) << 2)) + 16 * g;
        rbase[j8] = slot * 16;
    }

    // staging maps
    const int krow0 = tid >> 4;          // K: r (0..15), rows krow0+16j
    const int kg    = tid & 3;           // K: g'
    const int kk2   = (tid & 15) >> 2;   // K: d-chunk kk
    const int vq4   = tid & 31;          // V: d quad (dd = 4*vq4+jj)
    const int vc    = tid >> 5;          // V: kv chunk 0..7
    const int vhalf = vc >> 2, vg = vc & 3;

    f32x4 kreg[8], vreg[8];

    auto prefetch = [&](int kv0) {
        const float* kp = kbh + (size_t)(kv0 + krow0) * ROWSTR + (tid & 15) * 8;
#pragma unroll
        for (int jj = 0; jj < 4; ++jj) {
            kreg[2 * jj]     = *(const f32x4*)(kp + (size_t)(16 * jj) * ROWSTR);
            kreg[2 * jj + 1] = *(const f32x4*)(kp + (size_t)(16 * jj) * ROWSTR + 4);
        }
        const float* vp = vbh + (size_t)(kv0 + 32 * vhalf + 4 * vg) * ROWSTR + vq4 * 4;
#pragma unroll
        for (int i = 0; i < 4; ++i) {
            vreg[i]     = *(const f32x4*)(vp + (size_t)i * ROWSTR);
            vreg[4 + i] = *(const f32x4*)(vp + (size_t)(16 + i) * ROWSTR);
        }
    };

    auto stage = [&](char* base) {
#pragma unroll
        for (int jj = 0; jj < 4; ++jj) {
            int f = 4 * jj + kk2;
            int phi = (f >> 1) & 3, psi = f & 1;
            int slot = (krow0 ^ ((kg ^ phi) & 3) ^ ((psi ^ (krow0 >> 3)) << 2)) + 16 * kg;
            s16x8 t; unsigned* tu = (unsigned*)&t;
            tu[0] = pk2bf(kreg[2 * jj][0],     kreg[2 * jj][1]);
            tu[1] = pk2bf(kreg[2 * jj][2],     kreg[2 * jj][3]);
            tu[2] = pk2bf(kreg[2 * jj + 1][0], kreg[2 * jj + 1][1]);
            tu[3] = pk2bf(kreg[2 * jj + 1][2], kreg[2 * jj + 1][3]);
            *(s16x8*)(base + f * 1024 + slot * 16) = t;
        }
#pragma unroll
        for (int jj = 0; jj < 4; ++jj) {
            int dd = 4 * vq4 + jj;
            int f = (dd >> 4) * 2 + vhalf;
            int phi = (dd >> 4) & 3, psi = vhalf;
            int r = dd & 15;
            int slot = (r ^ ((vg ^ phi) & 3) ^ ((psi ^ (r >> 3)) << 2)) + 16 * vg;
            s16x8 t; unsigned* tu = (unsigned*)&t;
            tu[0] = pk2bf(vreg[0][jj], vreg[1][jj]);
            tu[1] = pk2bf(vreg[2][jj], vreg[3][jj]);
            tu[2] = pk2bf(vreg[4][jj], vreg[5][jj]);
            tu[3] = pk2bf(vreg[6][jj], vreg[7][jj]);
            *(s16x8*)(base + 16384 + f * 1024 + slot * 16) = t;
        }
    };

    const int nt = 2 * qt + 2;
    const int qb = qt * QBLK;
    const int qr0 = qb + 32 * w + lr;     // qh=0 row; qh=1 row = qr0+16

    s16x8 qf[2][4];
#pragma unroll
    for (int qh = 0; qh < 2; ++qh)
#pragma unroll
        for (int kk = 0; kk < 4; ++kk) {
            const float* qp = qbh + (size_t)(qr0 + 16 * qh) * ROWSTR + kk * 32 + g * 8;
            f32x4 a = *(const f32x4*)qp, b = *(const f32x4*)(qp + 4);
            unsigned* tu = (unsigned*)&qf[qh][kk];
            tu[0] = pk2bf(a[0] * QSCALE, a[1] * QSCALE);
            tu[1] = pk2bf(a[2] * QSCALE, a[3] * QSCALE);
            tu[2] = pk2bf(b[0] * QSCALE, b[1] * QSCALE);
            tu[3] = pk2bf(b[2] * QSCALE, b[3] * QSCALE);
        }

    f32x4 acc[8][2];
#pragma unroll
    for (int i = 0; i < 8; ++i) { acc[i][0] = (f32x4){0,0,0,0}; acc[i][1] = (f32x4){0,0,0,0}; }
    float mrun[2] = { -INFINITY, -INFINITY };
    float lrun[2] = { 0.f, 0.f };

    prefetch(0);
    stage(lds[0]);
    prefetch(KVBLK);
    __syncthreads();

    for (int t = 0; t < nt; ++t) {
        const int cur = t & 1;

        if (t + 1 < nt) {
            stage(lds[cur ^ 1]);                    // tile t+1 (regs ready)
            if (t + 2 < nt) prefetch((t + 2) * KVBLK);
        }

        const char* bK = lds[cur];
        const char* bV = lds[cur] + 16384;
        const int kv0 = t * KVBLK;
        const int wqmin = qb + 32 * w;              // wave's min q-row

        if (kv0 <= wqmin + 31) {                    // wave-uniform causal skip
            // ---- S^T = K · Q^T : sa[m][qh], kv = kv0+16m+4g+r, q = qr0+16qh
            f32x4 sa[4][2];
#pragma unroll
            for (int m = 0; m < 4; ++m) { sa[m][0] = (f32x4){0,0,0,0}; sa[m][1] = (f32x4){0,0,0,0}; }
            __builtin_amdgcn_s_setprio(1);
#pragma unroll
            for (int m = 0; m < 4; ++m)
#pragma unroll
                for (int kk = 0; kk < 4; ++kk) {
                    int f = 4 * m + kk;
                    s16x8 kf = *(const s16x8*)(bK + rbase[f & 7] + f * 1024);
                    sa[m][0] = __builtin_amdgcn_mfma_f32_16x16x32_bf16(kf, qf[0][kk], sa[m][0], 0, 0, 0);
                    sa[m][1] = __builtin_amdgcn_mfma_f32_16x16x32_bf16(kf, qf[1][kk], sa[m][1], 0, 0, 0);
                }
            __builtin_amdgcn_s_setprio(0);

            const bool maskt = (kv0 + KVBLK - 1 > wqmin);
            float mxv[2];
#pragma unroll
            for (int qh = 0; qh < 2; ++qh) {
                int qrow = qr0 + 16 * qh;
                if (maskt) {
#pragma unroll
                    for (int m = 0; m < 4; ++m)
#pragma unroll
                        for (int r = 0; r < 4; ++r)
                            if (kv0 + 16 * m + 4 * g + r > qrow) sa[m][qh][r] = -INFINITY;
                }
                float mx = sa[0][qh][0];
#pragma unroll
                for (int m = 0; m < 4; ++m)
#pragma unroll
                    for (int r = 0; r < 4; ++r) mx = fmaxf(mx, sa[m][qh][r]);
                mx = fmaxf(mx, __shfl_xor(mx, 16));
                mx = fmaxf(mx, __shfl_xor(mx, 32));
                mxv[qh] = mx;
            }

            if (!__all((mxv[0] - mrun[0] <= 8.0f) && (mxv[1] - mrun[1] <= 8.0f))) {
#pragma unroll
                for (int qh = 0; qh < 2; ++qh) {
                    float mnew = fmaxf(mrun[qh], mxv[qh]);
                    float corr = __builtin_amdgcn_exp2f(mrun[qh] - mnew);
                    lrun[qh] *= corr;
#pragma unroll
                    for (int db = 0; db < 8; ++db)
#pragma unroll
                        for (int r = 0; r < 4; ++r) acc[db][qh][r] *= corr;
                    mrun[qh] = mnew;
                }
            }

#pragma unroll
            for (int qh = 0; qh < 2; ++qh) {
                float ts = 0.f;
#pragma unroll
                for (int m = 0; m < 4; ++m)
#pragma unroll
                    for (int r = 0; r < 4; ++r) {
                        float p = __builtin_amdgcn_exp2f(sa[m][qh][r] - mrun[qh]);
                        sa[m][qh][r] = p;
                        ts += p;
                    }
                ts += __shfl_xor(ts, 16);
                ts += __shfl_xor(ts, 32);
                lrun[qh] += ts;
            }

            // ---- pack P: pa[qh][hf] element (g,j) = P[q][kv0+32hf+16(j>>2)+4g+(j&3)]
            s16x8 pa[2][2];
#pragma unroll
            for (int qh = 0; qh < 2; ++qh)
#pragma unroll
                for (int hf = 0; hf < 2; ++hf) {
                    unsigned* pu = (unsigned*)&pa[qh][hf];
                    pu[0] = pk2bf(sa[2 * hf][qh][0],     sa[2 * hf][qh][1]);
                    pu[1] = pk2bf(sa[2 * hf][qh][2],     sa[2 * hf][qh][3]);
                    pu[2] = pk2bf(sa[2 * hf + 1][qh][0], sa[2 * hf + 1][qh][1]);
                    pu[3] = pk2bf(sa[2 * hf + 1][qh][2], sa[2 * hf + 1][qh][3]);
                }

            // ---- O^T += V^T · P^T
            __builtin_amdgcn_s_setprio(1);
#pragma unroll
            for (int db = 0; db < 8; ++db)
#pragma unroll
                for (int hf = 0; hf < 2; ++hf) {
                    int f = 2 * db + hf;
                    s16x8 vf = *(const s16x8*)(bV + rbase[f & 7] + f * 1024);
                    acc[db][0] = __builtin_amdgcn_mfma_f32_16x16x32_bf16(vf, pa[0][hf], acc[db][0], 0, 0, 0);
                    acc[db][1] = __builtin_amdgcn_mfma_f32_16x16x32_bf16(vf, pa[1][hf], acc[db][1], 0, 0, 0);
                }
            __builtin_amdgcn_s_setprio(0);
        }
        __syncthreads();
    }

    // ---- epilogue: lane holds O[qr0+16qh][d = db*16 + 4g + r]
#pragma unroll
    for (int qh = 0; qh < 2; ++qh) {
        float inv = 1.0f / lrun[qh];
        float* op = out + (size_t)(qr0 + 16 * qh) * ROWSTR + bh * DDIM;
#pragma unroll
        for (int db = 0; db < 8; ++db) {
            f32x4 o;
#pragma unroll
            for (int r = 0; r < 4; ++r) o[r] = acc[db][qh][r] * inv;
            *(f32x4*)(op + db * 16 + g * 4) = o;
        }
    }
}

extern "C" void kernel_launch(void* const* d_in, const int* in_sizes, int n_in,
                              void* d_out, int out_size, void* d_ws, size_t ws_size,
                              hipStream_t stream) {
    const float* q = (const float*)d_in[0];
    const float* k = (const float*)d_in[1];
    const float* v = (const float*)d_in[2];
    float* o = (float*)d_out;
    dim3 grid(32 * NQT);   // 512 = 2 x 256 CUs, all co-resident
    dim3 block(256);
    fattn_kernel<<<grid, block, 0, stream>>>(q, k, v, o);
}